// Round 6
// baseline (1066.148 us; speedup 1.0000x reference)
//
#include <hip/hip_runtime.h>
#include <hip/hip_bf16.h>

// ---------------------------------------------------------------------------
// DeepSeek decoder layer. f32 inputs/outputs; internal bf16 (+f32 residual).
// GEMM: global_load_lds (16B DMA) double-buffered staging, one barrier per
// K-step (BK=64). W kept f32 in LDS, converted to bf16 at fragment read.
// LDS linear (DMA requirement); bank conflicts killed by pre-swizzling the
// per-lane GLOBAL source with slot^(row&7) and XOR-ing the same key on reads.
// ---------------------------------------------------------------------------

typedef __attribute__((ext_vector_type(4))) float  f32x4;
typedef __attribute__((ext_vector_type(8))) short  short8;
typedef __attribute__((ext_vector_type(8))) unsigned short ushort8;

#define SS    512
#define DD    2048
#define NH    16
#define HDIM  128
#define NQKV  6144
#define NEXP  64
#define TOPK  6
#define IEXP  1408
#define ISHE  2816
#define MAXTILE 112
#define ATT_SCALE 0.08838834764831845f

__device__ __forceinline__ float u2f(unsigned short u) {
  return __uint_as_float(((unsigned int)u) << 16);
}
__device__ __forceinline__ unsigned short f2u(float f) {
  __hip_bfloat16 h = __float2bfloat16(f);   // RNE
  return *reinterpret_cast<unsigned short*>(&h);
}
// two f32x4 -> short8 of bf16 bit patterns
__device__ __forceinline__ short8 cvt8s(f32x4 a, f32x4 b) {
  short8 r;
  r[0]=(short)f2u(a[0]); r[1]=(short)f2u(a[1]); r[2]=(short)f2u(a[2]); r[3]=(short)f2u(a[3]);
  r[4]=(short)f2u(b[0]); r[5]=(short)f2u(b[1]); r[6]=(short)f2u(b[2]); r[7]=(short)f2u(b[3]);
  return r;
}

typedef __attribute__((address_space(3))) unsigned int lds_uint;
typedef const __attribute__((address_space(1))) unsigned int ga_uint;
__device__ __forceinline__ void gll16(const void* g, void* l) {
  __builtin_amdgcn_global_load_lds((ga_uint*)g, (lds_uint*)l, 16, 0, 0);
}

// ---------------- fused add + rmsnorm (#1: f32 in, bf16 h1, f32 x1) ---------
__global__ __launch_bounds__(256) void addnorm1_k(
    const float* __restrict__ hid, const float* __restrict__ res,
    const float* __restrict__ w, float* __restrict__ x1,
    unsigned short* __restrict__ h1)
{
  int t = blockIdx.x, tid = threadIdx.x;
  long long base = (long long)t * DD + tid * 8;
  float x[8]; float ss = 0.f;
#pragma unroll
  for (int i = 0; i < 8; i++) {
    x[i] = hid[base + i] + res[base + i];
    ss += x[i] * x[i]; x1[base + i] = x[i];
  }
#pragma unroll
  for (int o = 1; o < 64; o <<= 1) ss += __shfl_xor(ss, o);
  __shared__ float r4[4];
  if ((tid & 63) == 0) r4[tid >> 6] = ss;
  __syncthreads();
  ss = r4[0] + r4[1] + r4[2] + r4[3];
  float rr = rsqrtf(ss * (1.f / DD) + 1e-6f);
#pragma unroll
  for (int i = 0; i < 8; i++) h1[base + i] = f2u(x[i] * rr * w[tid * 8 + i]);
}

// ------- fused add + rmsnorm (#2: bf16 attnout + f32 x1; resid->d_out f32) --
__global__ __launch_bounds__(256) void addnorm2_k(
    const unsigned short* __restrict__ attn, const float* __restrict__ x1,
    const float* __restrict__ w, float* __restrict__ resid_out,
    unsigned short* __restrict__ h3)
{
  int t = blockIdx.x, tid = threadIdx.x;
  long long base = (long long)t * DD + tid * 8;
  ushort8 va = *(const ushort8*)(attn + base);
  float x[8]; float ss = 0.f;
#pragma unroll
  for (int i = 0; i < 8; i++) {
    x[i] = u2f(va[i]) + x1[base + i]; ss += x[i] * x[i];
    resid_out[base + i] = x[i];
  }
#pragma unroll
  for (int o = 1; o < 64; o <<= 1) ss += __shfl_xor(ss, o);
  __shared__ float r4[4];
  if ((tid & 63) == 0) r4[tid >> 6] = ss;
  __syncthreads();
  ss = r4[0] + r4[1] + r4[2] + r4[3];
  float rr = rsqrtf(ss * (1.f / DD) + 1e-6f);
#pragma unroll
  for (int i = 0; i < 8; i++) h3[base + i] = f2u(x[i] * rr * w[tid * 8 + i]);
}

// ---------------------------------------------------------------------------
// global_load_lds double-buffered GEMM. C[m][n] = sum_k A[m][k]*W[n][k].
// A bf16 internal (LDS [64][64] bf16, 8 slots/row of 16B, source-swizzled by
// slot^(row&7)); W f32 raw (LDS [64][64] f32, 16 slots/row, same swizzle).
// 64x64 tile, 4 waves (2x2 of 32x32), BK=64, one barrier per K-step.
// SILU: W = [gate | up] rows; C = silu(g)*u. tile_tab!=null -> expert mode.
// GATHER: A row via tok_list. SCALE: epilogue *= wslot[crow].
// K and N multiples of 64.
// ---------------------------------------------------------------------------
template<bool SILU, bool GATHER, bool SCALE>
__global__ __launch_bounds__(256) void egemm_t(
    const unsigned short* __restrict__ A, const float* __restrict__ W,
    unsigned short* __restrict__ C, int Nh, int K, int lda, int Mdense,
    long long w_estride,
    const int* __restrict__ e_cnt, const int* __restrict__ e_off,
    const int* __restrict__ tok_list, const float* __restrict__ wslot,
    const int* __restrict__ tile_tab, const int* __restrict__ ntiles)
{
  __shared__ __align__(16) unsigned short As[2][64][64];
  __shared__ __align__(16) float Gs[2][64][64];
  __shared__ __align__(16) float Us[SILU ? 2 : 1][64][64];

  int cnt, roff = 0, m0;
  const float* Wb = W;
  if (tile_tab) {
    int y = blockIdx.y;
    if (y >= *ntiles) return;
    int tt = tile_tab[y];
    int e = tt >> 8;
    m0 = (tt & 255) * 64;
    cnt = e_cnt[e]; roff = e_off[e];
    Wb = W + (long long)e * w_estride;
  } else { m0 = blockIdx.y * 64; cnt = Mdense; }
  int n0 = blockIdx.x * 64;

  int tid = threadIdx.x, lane = tid & 63, w = tid >> 6;

  // ---- per-lane swizzled global source pointers (computed once) ----
  // A: wave w stages chunks {w, w+4}; chunk = 8 rows x 128B; lane: row=c*8+(l>>3), slot=l&7
  const unsigned short* asrc[2];
#pragma unroll
  for (int i = 0; i < 2; i++) {
    int c = w + i * 4;
    int am = m0 + c * 8 + (lane >> 3);
    if (am >= cnt) am = cnt - 1;
    int arow = GATHER ? tok_list[roff + am] : (tile_tab ? roff + am : am);
    asrc[i] = A + (long long)arow * lda + (((lane & 7) ^ (lane >> 3)) << 3);
  }
  // W: wave w stages chunks {w*4..w*4+3}; chunk = 4 rows x 256B; lane: row=c*4+(l>>4), slot=l&15
  const float* gsrc[4]; const float* usrc[4];
#pragma unroll
  for (int j = 0; j < 4; j++) {
    int c = w * 4 + j;
    int r = c * 4 + (lane >> 4);                    // row within tile
    int col = ((lane & 15) ^ (r & 7)) << 2;         // swizzled f32 col
    gsrc[j] = Wb + (long long)(n0 + r) * K + col;
    if (SILU) usrc[j] = Wb + (long long)(Nh + n0 + r) * K + col;
  }

  int wm = (w >> 1) * 32, wn = (w & 1) * 32;
  int l15 = lane & 15, hi = lane >> 4;
  int key = l15 & 7;                                 // row&7 for fragment rows

  f32x4 acc[2][2] = {}, accU[2][2] = {};

#define STAGE(buf, k0)                                                     \
  do {                                                                     \
    gll16((const char*)asrc[0] + (k0) * 2, &As[buf][w * 8][0]);            \
    gll16((const char*)asrc[1] + (k0) * 2, &As[buf][(w + 4) * 8][0]);      \
    _Pragma("unroll")                                                      \
    for (int j_ = 0; j_ < 4; j_++) {                                       \
      gll16((const char*)gsrc[j_] + (k0) * 4, &Gs[buf][(w * 4 + j_) * 4][0]); \
      if (SILU) gll16((const char*)usrc[j_] + (k0) * 4, &Us[buf][(w * 4 + j_) * 4][0]); \
    }                                                                      \
  } while (0)

  STAGE(0, 0);
  int buf = 0;
  for (int k0 = 0; k0 < K; k0 += 64, buf ^= 1) {
    __syncthreads();                       // buf staged (vmcnt drained); prev reads done
    if (k0 + 64 < K) STAGE(buf ^ 1, k0 + 64);
#pragma unroll
    for (int kk = 0; kk < 2; kk++) {
      short8 fa[2], fg[2];
#pragma unroll
      for (int f = 0; f < 2; f++) {
        int ra = wm + f * 16 + l15;
        fa[f] = *(const short8*)&As[buf][ra][(((kk << 2) + hi) ^ key) << 3];
        int rb = wn + f * 16 + l15;
        int s0 = (kk << 3) + (hi << 1);
        f32x4 g0 = *(const f32x4*)&Gs[buf][rb][(s0 ^ key) << 2];
        f32x4 g1 = *(const f32x4*)&Gs[buf][rb][((s0 + 1) ^ key) << 2];
        fg[f] = cvt8s(g0, g1);
      }
#pragma unroll
      for (int fm = 0; fm < 2; fm++)
#pragma unroll
        for (int fn = 0; fn < 2; fn++)
          acc[fm][fn] = __builtin_amdgcn_mfma_f32_16x16x32_bf16(fa[fm], fg[fn], acc[fm][fn], 0, 0, 0);
      if (SILU) {
        short8 fu[2];
#pragma unroll
        for (int f = 0; f < 2; f++) {
          int rb = wn + f * 16 + l15;
          int s0 = (kk << 3) + (hi << 1);
          f32x4 u0 = *(const f32x4*)&Us[buf][rb][(s0 ^ key) << 2];
          f32x4 u1 = *(const f32x4*)&Us[buf][rb][((s0 + 1) ^ key) << 2];
          fu[f] = cvt8s(u0, u1);
        }
#pragma unroll
        for (int fm = 0; fm < 2; fm++)
#pragma unroll
          for (int fn = 0; fn < 2; fn++)
            accU[fm][fn] = __builtin_amdgcn_mfma_f32_16x16x32_bf16(fa[fm], fu[fn], accU[fm][fn], 0, 0, 0);
      }
    }
  }
#undef STAGE

  int r0q = hi * 4;
#pragma unroll
  for (int fm = 0; fm < 2; fm++) {
#pragma unroll
    for (int j = 0; j < 4; j++) {
      int m = m0 + wm + fm * 16 + r0q + j;
      if (m >= cnt) continue;
      long long crow = tile_tab ? (long long)(roff + m) : m;
      float scale = SCALE ? wslot[crow] : 1.f;
      unsigned short* Cp = C + crow * (long long)Nh + n0 + wn;
#pragma unroll
      for (int fn = 0; fn < 2; fn++) {
        float v;
        if (SILU) {
          float g = acc[fm][fn][j], u = accU[fm][fn][j];
          v = (g / (1.f + __expf(-g))) * u;
        } else v = acc[fm][fn][j];
        Cp[fn * 16 + l15] = f2u(v * scale);
      }
    }
  }
}

// ------------------------------ RoPE (neox) --------------------------------
__global__ __launch_bounds__(256) void rope_k(
    const int* __restrict__ pos, const unsigned short* __restrict__ qkv,
    unsigned short* __restrict__ qr, unsigned short* __restrict__ kr)
{
  int t = blockIdx.x, tid = threadIdx.x;
  __shared__ float cs[64], sn[64];
  if (tid < 64) {
    float inv = __expf(-((float)(2 * tid) / 128.f) * logf(10000.f));
    float ang = (float)pos[t] * inv;
    cs[tid] = cosf(ang); sn[tid] = sinf(ang);
  }
  __syncthreads();
  const unsigned short* row = qkv + (long long)t * NQKV;
  for (int idx = tid; idx < NH * 64; idx += 256) {
    int hh = idx >> 6, i = idx & 63;
    long long o = ((long long)hh * SS + t) * HDIM;
    float x1 = u2f(row[hh*128 + i]), x2 = u2f(row[hh*128 + i + 64]);
    qr[o + i]      = f2u(x1 * cs[i] - x2 * sn[i]);
    qr[o + i + 64] = f2u(x2 * cs[i] + x1 * sn[i]);
    float y1 = u2f(row[2048 + hh*128 + i]), y2 = u2f(row[2048 + hh*128 + i + 64]);
    kr[o + i]      = f2u(y1 * cs[i] - y2 * sn[i]);
    kr[o + i + 64] = f2u(y2 * cs[i] + y1 * sn[i]);
  }
}

// ------------------- MFMA flash attention, 64 q-rows / block ----------------
__global__ __launch_bounds__(256) void attn_k(
    const unsigned short* __restrict__ qr, const unsigned short* __restrict__ kr,
    const unsigned short* __restrict__ qkv, unsigned short* __restrict__ ctx)
{
  int h = blockIdx.x, qt = blockIdx.y, q0 = qt * 64;
  int tid = threadIdx.x, lane = tid & 63, w = tid >> 6;
  int l15 = lane & 15, hi = lane >> 4;

  __shared__ unsigned short Vt[128][72];
  __shared__ unsigned short Pl[4][16][72];

  short8 qf[4];
  const unsigned short* Qb = qr + ((long long)h * SS + q0 + w * 16 + l15) * HDIM + hi * 8;
#pragma unroll
  for (int kf = 0; kf < 4; kf++) qf[kf] = *(const short8*)(Qb + kf * 32);

  f32x4 o[8] = {};
  float m_run[4] = {-1e30f, -1e30f, -1e30f, -1e30f};
  float l_run[4] = {};
  int myq = w * 16 + hi * 4;

  int ntile = qt + 1;
  for (int kt = 0; kt < ntile; kt++) {
    int kbase = kt * 64;
    __syncthreads();
    {
      int r = lane, d0 = w * 32;
      const unsigned short* Vp = qkv + (long long)(kbase + r) * NQKV + 4096 + h * HDIM + d0;
#pragma unroll
      for (int c = 0; c < 4; c++) {
        ushort8 v = *(const ushort8*)(Vp + c * 8);
#pragma unroll
        for (int i = 0; i < 8; i++) Vt[d0 + c * 8 + i][r] = v[i];
      }
    }
    f32x4 s[4] = {};
    const unsigned short* Kb = kr + ((long long)h * SS + kbase) * HDIM + hi * 8;
#pragma unroll
    for (int nf = 0; nf < 4; nf++) {
      const unsigned short* Kp = Kb + (long long)(nf * 16 + l15) * HDIM;
#pragma unroll
      for (int kf = 0; kf < 4; kf++) {
        short8 kf8 = *(const short8*)(Kp + kf * 32);
        s[nf] = __builtin_amdgcn_mfma_f32_16x16x32_bf16(qf[kf], kf8, s[nf], 0, 0, 0);
      }
    }
    bool diag = (kt == qt);
#pragma unroll
    for (int nf = 0; nf < 4; nf++) {
      int keyl = nf * 16 + l15;
#pragma unroll
      for (int j = 0; j < 4; j++) {
        float sv = s[nf][j] * ATT_SCALE;
        if (diag && keyl > myq + j) sv = -1e30f;
        s[nf][j] = sv;
      }
    }
    float corr[4], mnew[4];
#pragma unroll
    for (int j = 0; j < 4; j++) {
      float mv = fmaxf(fmaxf(s[0][j], s[1][j]), fmaxf(s[2][j], s[3][j]));
#pragma unroll
      for (int ox = 1; ox < 16; ox <<= 1) mv = fmaxf(mv, __shfl_xor(mv, ox));
      mnew[j] = fmaxf(m_run[j], mv);
      corr[j] = __expf(m_run[j] - mnew[j]);
      m_run[j] = mnew[j];
    }
#pragma unroll
    for (int nf8 = 0; nf8 < 8; nf8++)
#pragma unroll
      for (int j = 0; j < 4; j++) o[nf8][j] *= corr[j];
    float rs[4] = {};
#pragma unroll
    for (int nf = 0; nf < 4; nf++) {
#pragma unroll
      for (int j = 0; j < 4; j++) {
        float pv = __expf(s[nf][j] - mnew[j]);
        rs[j] += pv;
        Pl[w][hi * 4 + j][nf * 16 + l15] = f2u(pv);
      }
    }
#pragma unroll
    for (int j = 0; j < 4; j++) {
      float sv = rs[j];
#pragma unroll
      for (int ox = 1; ox < 16; ox <<= 1) sv += __shfl_xor(sv, ox);
      l_run[j] = l_run[j] * corr[j] + sv;
    }
    __syncthreads();
#pragma unroll
    for (int kf2 = 0; kf2 < 2; kf2++) {
      short8 pa = *(const short8*)&Pl[w][l15][kf2 * 32 + hi * 8];
#pragma unroll
      for (int nf8 = 0; nf8 < 8; nf8++) {
        short8 vb = *(const short8*)&Vt[nf8 * 16 + l15][kf2 * 32 + hi * 8];
        o[nf8] = __builtin_amdgcn_mfma_f32_16x16x32_bf16(pa, vb, o[nf8], 0, 0, 0);
      }
    }
  }
#pragma unroll
  for (int j = 0; j < 4; j++) {
    float inv = 1.f / l_run[j];
    long long t = q0 + myq + j;
    unsigned short* Cp = ctx + t * (long long)DD + h * HDIM;
#pragma unroll
    for (int nf8 = 0; nf8 < 8; nf8++)
      Cp[nf8 * 16 + l15] = f2u(o[nf8][j] * inv);
  }
}

// ------------------------------- gating ------------------------------------
__global__ __launch_bounds__(64) void gating_k(
    const unsigned short* __restrict__ h3, const float* __restrict__ gw,
    int* __restrict__ topi, float* __restrict__ topw)
{
  int t = blockIdx.x, e = threadIdx.x;
  __shared__ float p[NEXP];
  const unsigned short* hr = h3 + (long long)t * DD;
  const float* wr = gw + (long long)e * DD;
  float acc = 0.f;
  for (int k = 0; k < DD; k += 8) {
    ushort8 a = *(const ushort8*)(hr + k);
    f32x4 b0 = *(const f32x4*)(wr + k);
    f32x4 b1 = *(const f32x4*)(wr + k + 4);
    acc += u2f(a[0])*b0[0] + u2f(a[1])*b0[1] + u2f(a[2])*b0[2] + u2f(a[3])*b0[3]
         + u2f(a[4])*b1[0] + u2f(a[5])*b1[1] + u2f(a[6])*b1[2] + u2f(a[7])*b1[3];
  }
  p[e] = acc;
  __syncthreads();
  if (e == 0) {
    float mx = -1e30f;
    for (int j = 0; j < NEXP; j++) mx = fmaxf(mx, p[j]);
    float s = 0.f;
    for (int j = 0; j < NEXP; j++) { p[j] = __expf(p[j] - mx); s += p[j]; }
    float invs = 1.f / s;
    for (int j = 0; j < NEXP; j++) p[j] *= invs;
    for (int r = 0; r < TOPK; r++) {
      int bi = 0; float bv = -1.f;
      for (int j = 0; j < NEXP; j++) if (p[j] > bv) { bv = p[j]; bi = j; }
      topi[t * TOPK + r] = bi; topw[t * TOPK + r] = bv; p[bi] = -2.f;
    }
  }
}

// ------------------------------ routing ------------------------------------
__global__ __launch_bounds__(256) void route_k(
    const int* __restrict__ topi, const float* __restrict__ topw,
    int* __restrict__ ecnt, int* __restrict__ eoff,
    int* __restrict__ tok_list, int* __restrict__ slotg,
    float* __restrict__ wslot, int* __restrict__ tile_tab,
    int* __restrict__ ntiles)
{
  __shared__ int ti[SS * TOPK];
  __shared__ int c[NEXP];
  __shared__ int offs[NEXP + 1];
  int tid = threadIdx.x;
  for (int i = tid; i < SS * TOPK; i += 256) ti[i] = topi[i];
  __syncthreads();
  if (tid < NEXP) {
    int n = 0;
    for (int i = 0; i < SS * TOPK; i++) n += (ti[i] == tid);
    c[tid] = n; ecnt[tid] = n;
  }
  __syncthreads();
  if (tid == 0) {
    offs[0] = 0;
    for (int e = 0; e < NEXP; e++) offs[e + 1] = offs[e] + c[e];
    int nt = 0;
    for (int e = 0; e < NEXP; e++)
      for (int mt = 0; mt * 64 < c[e]; mt++) tile_tab[nt++] = (e << 8) | mt;
    *ntiles = nt;
  }
  __syncthreads();
  if (tid < NEXP) {
    int e = tid; eoff[e] = offs[e];
    int idx = offs[e];
    for (int i = 0; i < SS * TOPK; i++)
      if (ti[i] == e) {
        tok_list[idx] = i / TOPK; slotg[i] = idx; wslot[idx] = topw[i]; idx++;
      }
  }
}

// ------------------------------ combine ------------------------------------
__global__ __launch_bounds__(256) void combine_k(
    const unsigned short* __restrict__ shared_o, const unsigned short* __restrict__ out_e,
    const int* __restrict__ slotg, float* __restrict__ outp)
{
  int t = blockIdx.x, tid = threadIdx.x;
  int sl[TOPK];
#pragma unroll
  for (int j = 0; j < TOPK; j++) sl[j] = slotg[t * TOPK + j];
  long long d0 = (long long)t * DD + tid * 8;
  ushort8 sh = *(const ushort8*)(shared_o + d0);
  float a[8];
#pragma unroll
  for (int i = 0; i < 8; i++) a[i] = u2f(sh[i]);
#pragma unroll
  for (int j = 0; j < TOPK; j++) {
    ushort8 v = *(const ushort8*)(out_e + (long long)sl[j] * DD + tid * 8);
#pragma unroll
    for (int i = 0; i < 8; i++) a[i] += u2f(v[i]);
  }
#pragma unroll
  for (int i = 0; i < 8; i++) outp[d0 + i] = a[i];
}

// ---------------------------------------------------------------------------
extern "C" void kernel_launch(void* const* d_in, const int* in_sizes, int n_in,
                              void* d_out, int out_size, void* d_ws, size_t ws_size,
                              hipStream_t stream)
{
  (void)in_sizes; (void)n_in; (void)out_size; (void)ws_size;
  const int*   positions = (const int*)d_in[0];
  const float* hidden    = (const float*)d_in[1];
  const float* residual  = (const float*)d_in[2];
  const float* ln1_w     = (const float*)d_in[3];
  const float* ln2_w     = (const float*)d_in[4];
  const float* wqkv      = (const float*)d_in[5];
  const float* wo        = (const float*)d_in[6];
  const float* gate_w    = (const float*)d_in[7];
  const float* w1        = (const float*)d_in[8];
  const float* w2        = (const float*)d_in[9];
  const float* sw1       = (const float*)d_in[10];
  const float* sw2       = (const float*)d_in[11];

  float* outp      = (float*)d_out;
  float* resid_out = outp + (size_t)SS * DD;

  char* p = (char*)d_ws;
  auto alloc = [&](size_t b) { void* r = p; p += (b + 255) & ~(size_t)255; return r; };
  float*          x1       = (float*)alloc((size_t)SS * DD * 4);
  unsigned short* h1       = (unsigned short*)alloc((size_t)SS * DD * 2);
  unsigned short* qkv      = (unsigned short*)alloc((size_t)SS * NQKV * 2);
  unsigned short* qr       = (unsigned short*)alloc((size_t)SS * DD * 2);
  unsigned short* kr       = (unsigned short*)alloc((size_t)SS * DD * 2);
  unsigned short* ctx      = (unsigned short*)alloc((size_t)SS * DD * 2);
  unsigned short* attnout  = (unsigned short*)alloc((size_t)SS * DD * 2);
  unsigned short* h3       = (unsigned short*)alloc((size_t)SS * DD * 2);
  unsigned short* act_sh   = (unsigned short*)alloc((size_t)SS * ISHE * 2);
  unsigned short* shared_o = (unsigned short*)alloc((size_t)SS * DD * 2);
  unsigned short* act_e    = (unsigned short*)alloc((size_t)SS * TOPK * IEXP * 2);
  unsigned short* out_e    = (unsigned short*)alloc((size_t)SS * TOPK * DD * 2);
  int*            topi     = (int*)alloc(SS * TOPK * 4);
  float*          topw     = (float*)alloc(SS * TOPK * 4);
  int*            slotg    = (int*)alloc(SS * TOPK * 4);
  int*            tok_list = (int*)alloc(SS * TOPK * 4);
  float*          wslot    = (float*)alloc(SS * TOPK * 4);
  int*            ecnt     = (int*)alloc(NEXP * 4);
  int*            eoff     = (int*)alloc(NEXP * 4);
  int*            tile_tab = (int*)alloc(MAXTILE * 4);
  int*            ntiles   = (int*)alloc(4);

  addnorm1_k<<<SS, 256, 0, stream>>>(hidden, residual, ln1_w, x1, h1);
  egemm_t<false,false,false><<<dim3(NQKV/64, SS/64), 256, 0, stream>>>(
      h1, wqkv, qkv, NQKV, DD, DD, SS, 0, nullptr, nullptr, nullptr, nullptr, nullptr, nullptr);
  rope_k<<<SS, 256, 0, stream>>>(positions, qkv, qr, kr);
  attn_k<<<dim3(NH, SS/64), 256, 0, stream>>>(qr, kr, qkv, ctx);
  egemm_t<false,false,false><<<dim3(DD/64, SS/64), 256, 0, stream>>>(
      ctx, wo, attnout, DD, DD, DD, SS, 0, nullptr, nullptr, nullptr, nullptr, nullptr, nullptr);
  addnorm2_k<<<SS, 256, 0, stream>>>(attnout, x1, ln2_w, resid_out, h3);
  gating_k<<<SS, 64, 0, stream>>>(h3, gate_w, topi, topw);
  route_k<<<1, 256, 0, stream>>>(topi, topw, ecnt, eoff, tok_list, slotg, wslot,
                                 tile_tab, ntiles);
  egemm_t<true,true,false><<<dim3(IEXP/64, MAXTILE), 256, 0, stream>>>(
      h3, w1, act_e, IEXP, DD, DD, 0, (long long)2*IEXP*DD,
      ecnt, eoff, tok_list, nullptr, tile_tab, ntiles);
  egemm_t<false,false,true><<<dim3(DD/64, MAXTILE), 256, 0, stream>>>(
      act_e, w2, out_e, DD, IEXP, IEXP, 0, (long long)DD*IEXP,
      ecnt, eoff, nullptr, wslot, tile_tab, ntiles);
  egemm_t<true,false,false><<<dim3(ISHE/64, SS/64), 256, 0, stream>>>(
      h3, sw1, act_sh, ISHE, DD, DD, SS, 0, nullptr, nullptr, nullptr, nullptr, nullptr, nullptr);
  egemm_t<false,false,false><<<dim3(DD/64, SS/64), 256, 0, stream>>>(
      act_sh, sw2, shared_o, DD, ISHE, ISHE, SS, 0, nullptr, nullptr, nullptr, nullptr, nullptr, nullptr);
  combine_k<<<SS, 256, 0, stream>>>(shared_o, out_e, slotg, outp);
}